// Round 10
// baseline (59.443 us; speedup 1.0000x reference)
//
#include <hip/hip_runtime.h>
#include <hip/hip_bf16.h>

#define B_N 8
#define S_N 4096
#define D_N 64
#define NQT 64
#define TILE_BYTES 8192
#define SLOT_BYTES 4352  // 64 lanes*64B bf16-O + 64*4B l

typedef __attribute__((ext_vector_type(8))) short bf16x8;
typedef __attribute__((ext_vector_type(4))) float f32x4;
typedef __attribute__((ext_vector_type(16))) float f32x16;
typedef unsigned uint2v __attribute__((ext_vector_type(2)));
typedef unsigned uint4v __attribute__((ext_vector_type(4)));

__device__ __forceinline__ float fast_exp2(float x) {
#if __has_builtin(__builtin_amdgcn_exp2f)
  return __builtin_amdgcn_exp2f(x);
#else
  return exp2f(x);
#endif
}

__device__ __forceinline__ unsigned f2bf_u(float x) {
  __hip_bfloat16 h = __float2bfloat16(x);
  return (unsigned)__builtin_bit_cast(unsigned short, h);
}
__device__ __forceinline__ unsigned pack2(float a, float b) {
  return f2bf_u(a) | (f2bf_u(b) << 16);
}

// lane(i) <-> lane(i+32) exchange on the VALU pipe (not ds_bpermute).
__device__ __forceinline__ void pl32swap(unsigned& a, unsigned& b) {
#if __has_builtin(__builtin_amdgcn_permlane32_swap)
  uint2v r = __builtin_amdgcn_permlane32_swap(a, b, false, false);
  a = r[0];
  b = r[1];
#else
  asm volatile("v_permlane32_swap_b32 %0, %1" : "+v"(a), "+v"(b));
#endif
}
__device__ __forceinline__ float xhalf_sum(float x) {
  unsigned a = __builtin_bit_cast(unsigned, x), b = a;
  pl32swap(a, b);
  return __builtin_bit_cast(float, a) + __builtin_bit_cast(float, b);
}

// lens[b] = number of valid keys (prefix mask), write-only (no memset needed)
__global__ void __launch_bounds__(256)
lens_kernel(const unsigned* __restrict__ mask, int* __restrict__ lens) {
  int b = blockIdx.x, tid = threadIdx.x;
  unsigned first = mask[0];  // mask[0][0] always valid (len >= S/2)
  int cnt = 0;
  if (first == 0x01010101u) {          // bool / int8
    const unsigned char* m = ((const unsigned char*)mask) + (size_t)b * S_N;
    for (int i = tid; i < S_N; i += 256) cnt += (m[i] != 0);
  } else if (first == 0x3F800000u) {   // float
    const float* m = ((const float*)mask) + (size_t)b * S_N;
    for (int i = tid; i < S_N; i += 256) cnt += (m[i] != 0.0f);
  } else {                             // int32
    const int* m = ((const int*)mask) + (size_t)b * S_N;
    for (int i = tid; i < S_N; i += 256) cnt += (m[i] != 0);
  }
#pragma unroll
  for (int off = 32; off > 0; off >>= 1) cnt += __shfl_down(cnt, off);
  __shared__ int acc[4];
  if ((tid & 63) == 0) acc[tid >> 6] = cnt;
  __syncthreads();
  if (tid == 0) lens[b] = acc[0] + acc[1] + acc[2] + acc[3];
}

// One-time: K fp32 -> bf16 tiles, V fp32 -> V^T bf16 tiles, stored
// FRAGMENT-MAJOR: tile = [8 chunks][64 lanes][16B]. A wave fetches fragment
// f via one coalesced dwordx4 at tile + f*1024 + lane*16 -- no LDS staging.
__global__ void __launch_bounds__(256)
prep_kernel(const float* __restrict__ K, const float* __restrict__ V,
            char* __restrict__ Ks, char* __restrict__ VTs) {
  __shared__ float vl[64][72];  // V^T staging
  const int bt = blockIdx.x, tid = threadIdx.x;
  const float* Kt = K + (size_t)bt * 4096;
  const float* Vt = V + (size_t)bt * 4096;
  char* Ko = Ks + (size_t)bt * TILE_BYTES;
  char* Vo = VTs + (size_t)bt * TILE_BYTES;
#pragma unroll
  for (int i = 0; i < 2; ++i) {
    int c = tid + i * 256;
    int r = c >> 3, j = c & 7;
    f32x4 a = *(const f32x4*)(Kt + r * 64 + j * 8);
    f32x4 b4 = *(const f32x4*)(Kt + r * 64 + j * 8 + 4);
    union { bf16x8 v; unsigned u[4]; } pk;
    pk.u[0] = pack2(a[0], a[1]);   pk.u[1] = pack2(a[2], a[3]);
    pk.u[2] = pack2(b4[0], b4[1]); pk.u[3] = pack2(b4[2], b4[3]);
    *(bf16x8*)(Ko + ((r >> 5) * 4 + (j >> 1)) * 1024 + (j & 1) * 512 +
               (r & 31) * 16) = pk.v;
    f32x4 va = *(const f32x4*)(Vt + r * 64 + j * 8);
    f32x4 vb = *(const f32x4*)(Vt + r * 64 + j * 8 + 4);
#pragma unroll
    for (int e = 0; e < 4; ++e) vl[j * 8 + e][r] = va[e];
#pragma unroll
    for (int e = 0; e < 4; ++e) vl[j * 8 + 4 + e][r] = vb[e];
  }
  __syncthreads();
#pragma unroll
  for (int i = 0; i < 2; ++i) {
    int c = tid + i * 256;
    int d = c >> 3, j = c & 7;
    f32x4 fa = *(const f32x4*)(&vl[d][j * 8]);
    f32x4 fb = *(const f32x4*)(&vl[d][j * 8 + 4]);
    union { bf16x8 v; unsigned u[4]; } pk;
    pk.u[0] = pack2(fa[0], fa[1]); pk.u[1] = pack2(fa[2], fa[3]);
    pk.u[2] = pack2(fb[0], fb[1]); pk.u[3] = pack2(fb[2], fb[3]);
    *(bf16x8*)(Vo + ((d >> 5) * 4 + (j >> 1)) * 1024 + (j & 1) * 512 +
               (d & 31) * 16) = pk.v;
  }
}

// FOUR fully-independent waves per 256-thread block (no LDS, no barriers,
// no inter-wave interaction). Identical per-wave code to r9; the packing
// exists only to get past the per-CU workgroup-slot cap that pinned
// occupancy at ~4 waves/CU for 1-2-wave blocks (r8/r9 post-mortem).
// All 4 waves of a block share the batch b (XCD L2 pinning) and take
// adjacent LPT slots (similar lengths).
__global__ void __launch_bounds__(256)
attn_kernel(const float* __restrict__ Qg, const char* __restrict__ Ks,
            const char* __restrict__ VTs, const int* __restrict__ lens,
            float* __restrict__ Og, char* __restrict__ parts,
            int M, int U) {
  const int tid = threadIdx.x;
  const int lane = tid & 63;
  const int w = tid >> 6;                 // independent wave 0..3
  const int bid = blockIdx.x;
  const int b = bid & 7;                  // batch -> XCD pinning
  const int u2 = (bid >> 3) * 4 + w;      // task id within batch, 0..2U-1
  const int ws = u2 & 1;                  // q-half
  const int u = (U - 1) - (u2 >> 1);      // heavy slices first (LPT)
  // decode slot u -> (qt, s): group a has M q-tiles x (a+1) slots each
  int a = 0;
  while ((M * (a + 1) * (a + 2)) / 2 <= u) ++a;
  const int v = u - (M * a * (a + 1)) / 2;
  const int qt = a * M + v / (a + 1);
  const int s = v - (v / (a + 1)) * (a + 1);
  const int kq = a + 1;                   // splits for this q-tile

  const int q0 = qt * 64;
  const int len = lens[b];
  int nt = (len + 63) >> 6;
  if (qt + 1 < nt) nt = qt + 1;           // min(causal, padding); nt >= 1
  const int beg = s * M;
  int cnt = nt - beg;
  if (cnt > M) cnt = M;
  if (cnt < 0) cnt = 0;

  const int q31 = lane & 31;
  const int h = lane >> 5;
  const int qg = q0 + ws * 32 + q31;      // q-row this lane owns

  const char* Kb = Ks + (size_t)(b * NQT) * TILE_BYTES;
  const char* Vb = VTs + (size_t)(b * NQT) * TILE_BYTES;

  constexpr float CS = 0.125f * 1.4426950408889634f;  // scale * log2(e)
  bf16x8 qf[4];
#pragma unroll
  for (int c = 0; c < 4; ++c) {
    const float* src = Qg + ((size_t)(b * S_N) + qg) * D_N + c * 16 + h * 8;
    f32x4 aa = *(const f32x4*)src;
    f32x4 b4 = *(const f32x4*)(src + 4);
    union { bf16x8 v; unsigned u[4]; } pk;
    pk.u[0] = pack2(aa[0] * CS, aa[1] * CS);
    pk.u[1] = pack2(aa[2] * CS, aa[3] * CS);
    pk.u[2] = pack2(b4[0] * CS, b4[1] * CS);
    pk.u[3] = pack2(b4[2] * CS, b4[3] * CS);
    qf[c] = pk.v;
  }

  f32x16 ot0 = {}, ot1 = {};  // O^T accum (raw, unnormalized)
  float l = 0.0f;

  for (int j = 0; j < cnt; ++j) {
    const int t = beg + j;
    // ---- K fragments: 8 coalesced dwordx4 from L2 ----
    bf16x8 f[8];
    const char* Kt = Kb + (size_t)t * TILE_BYTES + lane * 16;
#pragma unroll
    for (int c = 0; c < 8; ++c) f[c] = *(const bf16x8*)(Kt + c * 1024);

    // ---- S^T = K . Q^T - 8 (fixed-max bias in C-init) ----
    f32x16 s0, s1;
#pragma unroll
    for (int i = 0; i < 16; ++i) { s0[i] = -8.0f; s1[i] = -8.0f; }
#pragma unroll
    for (int c = 0; c < 4; ++c) {
      s0 = __builtin_amdgcn_mfma_f32_32x32x16_bf16(f[c], qf[c], s0, 0, 0, 0);
      s1 = __builtin_amdgcn_mfma_f32_32x32x16_bf16(f[4 + c], qf[c], s1, 0, 0, 0);
    }

    // ---- V fragments issued now; consumed after softmax (~700cy) ----
    const char* Vt2 = Vb + (size_t)t * TILE_BYTES + lane * 16;
#pragma unroll
    for (int c = 0; c < 8; ++c) f[c] = *(const bf16x8*)(Vt2 + c * 1024);

    const int kv0 = t * 64;
    if (t == qt || kv0 + 64 > len) {     // diagonal or padding boundary
#pragma unroll
      for (int g = 0; g < 4; ++g)
#pragma unroll
        for (int jj = 0; jj < 4; ++jj) {
          int kl = 8 * g + 4 * h + jj;
          if (kv0 + kl > qg || kv0 + kl >= len) s0[g * 4 + jj] = -10000.0f;
          if (kv0 + 32 + kl > qg || kv0 + 32 + kl >= len) s1[g * 4 + jj] = -10000.0f;
        }
    }

    // ---- p = exp2(s) (already biased), l += sum p ----
    float ps0 = 0.f, ps1 = 0.f, ps2 = 0.f, ps3 = 0.f;
#pragma unroll
    for (int g = 0; g < 4; ++g) {
      s0[4 * g + 0] = fast_exp2(s0[4 * g + 0]); ps0 += s0[4 * g + 0];
      s0[4 * g + 1] = fast_exp2(s0[4 * g + 1]); ps1 += s0[4 * g + 1];
      s0[4 * g + 2] = fast_exp2(s0[4 * g + 2]); ps2 += s0[4 * g + 2];
      s0[4 * g + 3] = fast_exp2(s0[4 * g + 3]); ps3 += s0[4 * g + 3];
      s1[4 * g + 0] = fast_exp2(s1[4 * g + 0]); ps0 += s1[4 * g + 0];
      s1[4 * g + 1] = fast_exp2(s1[4 * g + 1]); ps1 += s1[4 * g + 1];
      s1[4 * g + 2] = fast_exp2(s1[4 * g + 2]); ps2 += s1[4 * g + 2];
      s1[4 * g + 3] = fast_exp2(s1[4 * g + 3]); ps3 += s1[4 * g + 3];
    }
    l += xhalf_sum((ps0 + ps1) + (ps2 + ps3));

    // ---- P^T B-frags in-register via permlane32_swap (T12) ----
    unsigned opk0[4][2], opk1[4][2];
#pragma unroll
    for (int g = 0; g < 4; ++g) {
      opk0[g][0] = pack2(s0[4 * g + 0], s0[4 * g + 1]);
      opk0[g][1] = pack2(s0[4 * g + 2], s0[4 * g + 3]);
      opk1[g][0] = pack2(s1[4 * g + 0], s1[4 * g + 1]);
      opk1[g][1] = pack2(s1[4 * g + 2], s1[4 * g + 3]);
    }
    bf16x8 pb[4];
#pragma unroll
    for (int c = 0; c < 4; ++c) {
      const unsigned(*o)[2] = (c < 2) ? opk0 : opk1;
      const int g0 = 2 * (c & 1), g1 = g0 + 1;
      unsigned a0 = o[g0][0], b0 = o[g1][0];
      unsigned a1 = o[g0][1], b1 = o[g1][1];
      pl32swap(a0, b0);
      pl32swap(a1, b1);
      union { bf16x8 v; unsigned u[4]; } pk;
      pk.u[0] = a0; pk.u[1] = a1; pk.u[2] = b0; pk.u[3] = b1;
      pb[c] = pk.v;
    }

    // ---- O^T += V^T . P^T ----
#pragma unroll
    for (int c = 0; c < 4; ++c) {
      ot0 = __builtin_amdgcn_mfma_f32_32x32x16_bf16(f[c], pb[c], ot0, 0, 0, 0);
      ot1 = __builtin_amdgcn_mfma_f32_32x32x16_bf16(f[4 + c], pb[c], ot1, 0, 0, 0);
    }
  }

  if (kq == 1) {
    // solo: normalize and write d_out directly
    float linv = 1.0f / l;
    float* orow = Og + ((size_t)(b * S_N) + qg) * D_N;
#pragma unroll
    for (int g = 0; g < 4; ++g) {
      f32x4 oa = {ot0[4 * g + 0] * linv, ot0[4 * g + 1] * linv,
                  ot0[4 * g + 2] * linv, ot0[4 * g + 3] * linv};
      *(f32x4*)(orow + 8 * g + 4 * h) = oa;
      f32x4 ob = {ot1[4 * g + 0] * linv, ot1[4 * g + 1] * linv,
                  ot1[4 * g + 2] * linv, ot1[4 * g + 3] * linv};
      *(f32x4*)(orow + 32 + 8 * g + 4 * h) = ob;
    }
  } else {
    // partial: bf16 O_raw (32 values -> 16 u32) + f32 l, per lane
    // (written even when cnt==0: zeros contribute nothing to the merge)
    char* slot = parts + (((size_t)b * U + u) * 2 + ws) * SLOT_BYTES;
    unsigned wv[16];
#pragma unroll
    for (int jj = 0; jj < 8; ++jj) {
      wv[jj] = pack2(ot0[2 * jj], ot0[2 * jj + 1]);
      wv[8 + jj] = pack2(ot1[2 * jj], ot1[2 * jj + 1]);
    }
    uint4v* dst = (uint4v*)(slot + lane * 64);
#pragma unroll
    for (int q4 = 0; q4 < 4; ++q4)
      dst[q4] = (uint4v){wv[4 * q4], wv[4 * q4 + 1], wv[4 * q4 + 2], wv[4 * q4 + 3]};
    *(float*)(slot + 4096 + lane * 4) = l;
  }
}

// merge kq partial slots of one (b, qt) -> normalized d_out
__global__ void __launch_bounds__(128)
merge_kernel(const char* __restrict__ parts, float* __restrict__ Og,
             int M, int U) {
  const int bid = blockIdx.x;
  const int b = bid & 7, qt = bid >> 3;
  const int a = qt / M;
  const int kq = a + 1;
  if (kq == 1) return;  // solo waves already wrote d_out
  const int tid = threadIdx.x;
  const int ws = tid >> 6;
  const int lane = tid & 63;
  const int base_u = (M * a * (a + 1)) / 2 + (qt - a * M) * (a + 1);

  float acc[32];
#pragma unroll
  for (int i = 0; i < 32; ++i) acc[i] = 0.0f;
  float L = 0.0f;
  for (int s2 = 0; s2 < kq; ++s2) {
    const char* slot =
        parts + (((size_t)b * U + base_u + s2) * 2 + ws) * SLOT_BYTES;
    const uint4v* src = (const uint4v*)(slot + lane * 64);
#pragma unroll
    for (int q4 = 0; q4 < 4; ++q4) {
      uint4v wv = src[q4];
#pragma unroll
      for (int e = 0; e < 4; ++e) {
        unsigned uw = wv[e];
        acc[2 * (4 * q4 + e)] += __builtin_bit_cast(float, uw << 16);
        acc[2 * (4 * q4 + e) + 1] += __builtin_bit_cast(float, uw & 0xFFFF0000u);
      }
    }
    L += *(const float*)(slot + 4096 + lane * 4);
  }
  float linv = 1.0f / L;
  const int q31 = lane & 31;
  const int h = lane >> 5;
  float* orow = Og + ((size_t)(b * S_N) + qt * 64 + ws * 32 + q31) * D_N;
#pragma unroll
  for (int dt = 0; dt < 2; ++dt)
#pragma unroll
    for (int g = 0; g < 4; ++g) {
      f32x4 w = {acc[dt * 16 + 4 * g + 0] * linv, acc[dt * 16 + 4 * g + 1] * linv,
                 acc[dt * 16 + 4 * g + 2] * linv, acc[dt * 16 + 4 * g + 3] * linv};
      *(f32x4*)(orow + dt * 32 + 8 * g + 4 * h) = w;
    }
}

extern "C" void kernel_launch(void* const* d_in, const int* in_sizes, int n_in,
                              void* d_out, int out_size, void* d_ws, size_t ws_size,
                              hipStream_t stream) {
  const float* Qg = (const float*)d_in[0];
  const float* Kg = (const float*)d_in[1];
  const float* Vg = (const float*)d_in[2];
  const unsigned* mask = (const unsigned*)d_in[3];
  float* Og = (float*)d_out;

  int* lens = (int*)d_ws;
  char* Ks = (char*)d_ws + 4096;
  char* VTs = Ks + (size_t)B_N * NQT * TILE_BYTES;    // +4MB
  char* parts = VTs + (size_t)B_N * NQT * TILE_BYTES; // +4MB

  // M = max tiles per wave; U = slots per batch = M*A*(A+1)/2, A = 64/M
  int M = 8, U = 288;
  size_t need = 4096 + ((size_t)2 * B_N * NQT * TILE_BYTES) +
                (size_t)B_N * 288 * 2 * SLOT_BYTES;   // ~28.1MB
  if (ws_size < need) { M = 64; U = 64; }             // no split, no partials

  lens_kernel<<<dim3(B_N), dim3(256), 0, stream>>>(mask, lens);
  prep_kernel<<<dim3(B_N * NQT), dim3(256), 0, stream>>>(Kg, Vg, Ks, VTs);
  // 4 independent waves per block: tasks 2U per batch, 4 per block
  attn_kernel<<<dim3(B_N * U / 2), dim3(256), 0, stream>>>(Qg, Ks, VTs, lens,
                                                           Og, parts, M, U);
  if (M == 8)
    merge_kernel<<<dim3(B_N * NQT), dim3(128), 0, stream>>>(parts, Og, M, U);
}

// Round 11
// 54.718 us; speedup vs baseline: 1.0863x; 1.0863x over previous
//
#include <hip/hip_runtime.h>
#include <hip/hip_bf16.h>

#define B_N 8
#define S_N 4096
#define D_N 64
#define NQT 64
#define TILE_BYTES 8192
#define SLOT_BYTES 4352  // 64 lanes*64B bf16-O + 64*4B l

typedef __attribute__((ext_vector_type(8))) short bf16x8;
typedef __attribute__((ext_vector_type(4))) float f32x4;
typedef __attribute__((ext_vector_type(16))) float f32x16;
typedef unsigned uint2v __attribute__((ext_vector_type(2)));
typedef unsigned uint4v __attribute__((ext_vector_type(4)));

__device__ __forceinline__ float fast_exp2(float x) {
#if __has_builtin(__builtin_amdgcn_exp2f)
  return __builtin_amdgcn_exp2f(x);
#else
  return exp2f(x);
#endif
}

__device__ __forceinline__ unsigned f2bf_u(float x) {
  __hip_bfloat16 h = __float2bfloat16(x);
  return (unsigned)__builtin_bit_cast(unsigned short, h);
}
__device__ __forceinline__ unsigned pack2(float a, float b) {
  return f2bf_u(a) | (f2bf_u(b) << 16);
}

// lane(i) <-> lane(i+32) exchange on the VALU pipe (not ds_bpermute).
__device__ __forceinline__ void pl32swap(unsigned& a, unsigned& b) {
#if __has_builtin(__builtin_amdgcn_permlane32_swap)
  uint2v r = __builtin_amdgcn_permlane32_swap(a, b, false, false);
  a = r[0];
  b = r[1];
#else
  asm volatile("v_permlane32_swap_b32 %0, %1" : "+v"(a), "+v"(b));
#endif
}
__device__ __forceinline__ float xhalf_sum(float x) {
  unsigned a = __builtin_bit_cast(unsigned, x), b = a;
  pl32swap(a, b);
  return __builtin_bit_cast(float, a) + __builtin_bit_cast(float, b);
}

// lens[b] = number of valid keys (prefix mask), write-only (no memset needed)
__global__ void __launch_bounds__(256)
lens_kernel(const unsigned* __restrict__ mask, int* __restrict__ lens) {
  int b = blockIdx.x, tid = threadIdx.x;
  unsigned first = mask[0];  // mask[0][0] always valid (len >= S/2)
  int cnt = 0;
  if (first == 0x01010101u) {          // bool / int8
    const unsigned char* m = ((const unsigned char*)mask) + (size_t)b * S_N;
    for (int i = tid; i < S_N; i += 256) cnt += (m[i] != 0);
  } else if (first == 0x3F800000u) {   // float
    const float* m = ((const float*)mask) + (size_t)b * S_N;
    for (int i = tid; i < S_N; i += 256) cnt += (m[i] != 0.0f);
  } else {                             // int32
    const int* m = ((const int*)mask) + (size_t)b * S_N;
    for (int i = tid; i < S_N; i += 256) cnt += (m[i] != 0);
  }
#pragma unroll
  for (int off = 32; off > 0; off >>= 1) cnt += __shfl_down(cnt, off);
  __shared__ int acc[4];
  if ((tid & 63) == 0) acc[tid >> 6] = cnt;
  __syncthreads();
  if (tid == 0) lens[b] = acc[0] + acc[1] + acc[2] + acc[3];
}

// One-time: K fp32 -> bf16 tiles, V fp32 -> V^T bf16 tiles, stored
// FRAGMENT-MAJOR: tile = [8 chunks][64 lanes][16B]. A wave fetches fragment
// f via one coalesced dwordx4 at tile + f*1024 + lane*16 -- no LDS staging.
__global__ void __launch_bounds__(256)
prep_kernel(const float* __restrict__ K, const float* __restrict__ V,
            char* __restrict__ Ks, char* __restrict__ VTs) {
  __shared__ float vl[64][72];  // V^T staging
  const int bt = blockIdx.x, tid = threadIdx.x;
  const float* Kt = K + (size_t)bt * 4096;
  const float* Vt = V + (size_t)bt * 4096;
  char* Ko = Ks + (size_t)bt * TILE_BYTES;
  char* Vo = VTs + (size_t)bt * TILE_BYTES;
#pragma unroll
  for (int i = 0; i < 2; ++i) {
    int c = tid + i * 256;
    int r = c >> 3, j = c & 7;
    f32x4 a = *(const f32x4*)(Kt + r * 64 + j * 8);
    f32x4 b4 = *(const f32x4*)(Kt + r * 64 + j * 8 + 4);
    union { bf16x8 v; unsigned u[4]; } pk;
    pk.u[0] = pack2(a[0], a[1]);   pk.u[1] = pack2(a[2], a[3]);
    pk.u[2] = pack2(b4[0], b4[1]); pk.u[3] = pack2(b4[2], b4[3]);
    *(bf16x8*)(Ko + ((r >> 5) * 4 + (j >> 1)) * 1024 + (j & 1) * 512 +
               (r & 31) * 16) = pk.v;
    f32x4 va = *(const f32x4*)(Vt + r * 64 + j * 8);
    f32x4 vb = *(const f32x4*)(Vt + r * 64 + j * 8 + 4);
#pragma unroll
    for (int e = 0; e < 4; ++e) vl[j * 8 + e][r] = va[e];
#pragma unroll
    for (int e = 0; e < 4; ++e) vl[j * 8 + 4 + e][r] = vb[e];
  }
  __syncthreads();
#pragma unroll
  for (int i = 0; i < 2; ++i) {
    int c = tid + i * 256;
    int d = c >> 3, j = c & 7;
    f32x4 fa = *(const f32x4*)(&vl[d][j * 8]);
    f32x4 fb = *(const f32x4*)(&vl[d][j * 8 + 4]);
    union { bf16x8 v; unsigned u[4]; } pk;
    pk.u[0] = pack2(fa[0], fa[1]); pk.u[1] = pack2(fa[2], fa[3]);
    pk.u[2] = pack2(fb[0], fb[1]); pk.u[3] = pack2(fb[2], fb[3]);
    *(bf16x8*)(Vo + ((d >> 5) * 4 + (j >> 1)) * 1024 + (j & 1) * 512 +
               (d & 31) * 16) = pk.v;
  }
}

// FOUR fully-independent waves per 256-thread block, no LDS, no barriers.
// NEW vs r10:
//  (1) __launch_bounds__(256, 2): cap unified VGPR+AGPR budget at 256/wave.
//      r9/r10 post-mortem: residency pinned at ~1 wave/SIMD though reported
//      VGPR=96 -- hidden accumulator (AGPR-side) allocation is the suspect.
//      256-reg cap (vs r5's fatal 128) fits the ~176-reg live set, no spill.
//  (2) In-wave K(t+1) prefetch: issue next tile's K right after QK^T
//      consumes the current one -- L2 latency hides under softmax+PV.
__global__ void __launch_bounds__(256, 2)
attn_kernel(const float* __restrict__ Qg, const char* __restrict__ Ks,
            const char* __restrict__ VTs, const int* __restrict__ lens,
            float* __restrict__ Og, char* __restrict__ parts,
            int M, int U) {
  const int tid = threadIdx.x;
  const int lane = tid & 63;
  const int w = tid >> 6;                 // independent wave 0..3
  const int bid = blockIdx.x;
  const int b = bid & 7;                  // batch -> XCD pinning
  const int u2 = (bid >> 3) * 4 + w;      // task id within batch, 0..2U-1
  const int ws = u2 & 1;                  // q-half
  const int u = (U - 1) - (u2 >> 1);      // heavy slices first (LPT)
  // decode slot u -> (qt, s): group a has M q-tiles x (a+1) slots each
  int a = 0;
  while ((M * (a + 1) * (a + 2)) / 2 <= u) ++a;
  const int v = u - (M * a * (a + 1)) / 2;
  const int qt = a * M + v / (a + 1);
  const int s = v - (v / (a + 1)) * (a + 1);
  const int kq = a + 1;                   // splits for this q-tile

  const int q0 = qt * 64;
  const int len = lens[b];
  int nt = (len + 63) >> 6;
  if (qt + 1 < nt) nt = qt + 1;           // min(causal, padding); nt >= 1
  const int beg = s * M;
  int cnt = nt - beg;
  if (cnt > M) cnt = M;
  if (cnt < 0) cnt = 0;

  const int q31 = lane & 31;
  const int h = lane >> 5;
  const int qg = q0 + ws * 32 + q31;      // q-row this lane owns

  const char* Kb = Ks + (size_t)(b * NQT) * TILE_BYTES;
  const char* Vb = VTs + (size_t)(b * NQT) * TILE_BYTES;

  constexpr float CS = 0.125f * 1.4426950408889634f;  // scale * log2(e)
  bf16x8 qf[4];
#pragma unroll
  for (int c = 0; c < 4; ++c) {
    const float* src = Qg + ((size_t)(b * S_N) + qg) * D_N + c * 16 + h * 8;
    f32x4 aa = *(const f32x4*)src;
    f32x4 b4 = *(const f32x4*)(src + 4);
    union { bf16x8 v; unsigned u[4]; } pk;
    pk.u[0] = pack2(aa[0] * CS, aa[1] * CS);
    pk.u[1] = pack2(aa[2] * CS, aa[3] * CS);
    pk.u[2] = pack2(b4[0] * CS, b4[1] * CS);
    pk.u[3] = pack2(b4[2] * CS, b4[3] * CS);
    qf[c] = pk.v;
  }

  f32x16 ot0 = {}, ot1 = {};  // O^T accum (raw, unnormalized)
  float l = 0.0f;

  // K(t) fragments live across the iteration; prefetched one tile ahead.
  bf16x8 ka[8];
  if (cnt > 0) {
    const char* Kt = Kb + (size_t)beg * TILE_BYTES + lane * 16;
#pragma unroll
    for (int c = 0; c < 8; ++c) ka[c] = *(const bf16x8*)(Kt + c * 1024);
  }

  for (int j = 0; j < cnt; ++j) {
    const int t = beg + j;

    // ---- S^T = K . Q^T - 8 (fixed-max bias in C-init); consumes ka ----
    f32x16 s0, s1;
#pragma unroll
    for (int i = 0; i < 16; ++i) { s0[i] = -8.0f; s1[i] = -8.0f; }
#pragma unroll
    for (int c = 0; c < 4; ++c) {
      s0 = __builtin_amdgcn_mfma_f32_32x32x16_bf16(ka[c], qf[c], s0, 0, 0, 0);
      s1 = __builtin_amdgcn_mfma_f32_32x32x16_bf16(ka[4 + c], qf[c], s1, 0, 0, 0);
    }

    // ---- V(t) fragments: issued now, consumed after softmax ----
    bf16x8 vv[8];
    const char* Vt2 = Vb + (size_t)t * TILE_BYTES + lane * 16;
#pragma unroll
    for (int c = 0; c < 8; ++c) vv[c] = *(const bf16x8*)(Vt2 + c * 1024);

    // ---- K(t+1) prefetch: lands during softmax + PV of tile t ----
    if (j + 1 < cnt) {
      const char* Kn = Kb + (size_t)(t + 1) * TILE_BYTES + lane * 16;
#pragma unroll
      for (int c = 0; c < 8; ++c) ka[c] = *(const bf16x8*)(Kn + c * 1024);
    }

    const int kv0 = t * 64;
    if (t == qt || kv0 + 64 > len) {     // diagonal or padding boundary
#pragma unroll
      for (int g = 0; g < 4; ++g)
#pragma unroll
        for (int jj = 0; jj < 4; ++jj) {
          int kl = 8 * g + 4 * h + jj;
          if (kv0 + kl > qg || kv0 + kl >= len) s0[g * 4 + jj] = -10000.0f;
          if (kv0 + 32 + kl > qg || kv0 + 32 + kl >= len) s1[g * 4 + jj] = -10000.0f;
        }
    }

    // ---- p = exp2(s) (already biased), l += sum p ----
    float ps0 = 0.f, ps1 = 0.f, ps2 = 0.f, ps3 = 0.f;
#pragma unroll
    for (int g = 0; g < 4; ++g) {
      s0[4 * g + 0] = fast_exp2(s0[4 * g + 0]); ps0 += s0[4 * g + 0];
      s0[4 * g + 1] = fast_exp2(s0[4 * g + 1]); ps1 += s0[4 * g + 1];
      s0[4 * g + 2] = fast_exp2(s0[4 * g + 2]); ps2 += s0[4 * g + 2];
      s0[4 * g + 3] = fast_exp2(s0[4 * g + 3]); ps3 += s0[4 * g + 3];
      s1[4 * g + 0] = fast_exp2(s1[4 * g + 0]); ps0 += s1[4 * g + 0];
      s1[4 * g + 1] = fast_exp2(s1[4 * g + 1]); ps1 += s1[4 * g + 1];
      s1[4 * g + 2] = fast_exp2(s1[4 * g + 2]); ps2 += s1[4 * g + 2];
      s1[4 * g + 3] = fast_exp2(s1[4 * g + 3]); ps3 += s1[4 * g + 3];
    }
    l += xhalf_sum((ps0 + ps1) + (ps2 + ps3));

    // ---- P^T B-frags in-register via permlane32_swap (T12) ----
    unsigned opk0[4][2], opk1[4][2];
#pragma unroll
    for (int g = 0; g < 4; ++g) {
      opk0[g][0] = pack2(s0[4 * g + 0], s0[4 * g + 1]);
      opk0[g][1] = pack2(s0[4 * g + 2], s0[4 * g + 3]);
      opk1[g][0] = pack2(s1[4 * g + 0], s1[4 * g + 1]);
      opk1[g][1] = pack2(s1[4 * g + 2], s1[4 * g + 3]);
    }
    bf16x8 pb[4];
#pragma unroll
    for (int c = 0; c < 4; ++c) {
      const unsigned(*o)[2] = (c < 2) ? opk0 : opk1;
      const int g0 = 2 * (c & 1), g1 = g0 + 1;
      unsigned a0 = o[g0][0], b0 = o[g1][0];
      unsigned a1 = o[g0][1], b1 = o[g1][1];
      pl32swap(a0, b0);
      pl32swap(a1, b1);
      union { bf16x8 v; unsigned u[4]; } pk;
      pk.u[0] = a0; pk.u[1] = a1; pk.u[2] = b0; pk.u[3] = b1;
      pb[c] = pk.v;
    }

    // ---- O^T += V^T . P^T ----
#pragma unroll
    for (int c = 0; c < 4; ++c) {
      ot0 = __builtin_amdgcn_mfma_f32_32x32x16_bf16(vv[c], pb[c], ot0, 0, 0, 0);
      ot1 = __builtin_amdgcn_mfma_f32_32x32x16_bf16(vv[4 + c], pb[c], ot1, 0, 0, 0);
    }
  }

  if (kq == 1) {
    // solo: normalize and write d_out directly
    float linv = 1.0f / l;
    float* orow = Og + ((size_t)(b * S_N) + qg) * D_N;
#pragma unroll
    for (int g = 0; g < 4; ++g) {
      f32x4 oa = {ot0[4 * g + 0] * linv, ot0[4 * g + 1] * linv,
                  ot0[4 * g + 2] * linv, ot0[4 * g + 3] * linv};
      *(f32x4*)(orow + 8 * g + 4 * h) = oa;
      f32x4 ob = {ot1[4 * g + 0] * linv, ot1[4 * g + 1] * linv,
                  ot1[4 * g + 2] * linv, ot1[4 * g + 3] * linv};
      *(f32x4*)(orow + 32 + 8 * g + 4 * h) = ob;
    }
  } else {
    // partial: bf16 O_raw (32 values -> 16 u32) + f32 l, per lane
    // (written even when cnt==0: zeros contribute nothing to the merge)
    char* slot = parts + (((size_t)b * U + u) * 2 + ws) * SLOT_BYTES;
    unsigned wv[16];
#pragma unroll
    for (int jj = 0; jj < 8; ++jj) {
      wv[jj] = pack2(ot0[2 * jj], ot0[2 * jj + 1]);
      wv[8 + jj] = pack2(ot1[2 * jj], ot1[2 * jj + 1]);
    }
    uint4v* dst = (uint4v*)(slot + lane * 64);
#pragma unroll
    for (int q4 = 0; q4 < 4; ++q4)
      dst[q4] = (uint4v){wv[4 * q4], wv[4 * q4 + 1], wv[4 * q4 + 2], wv[4 * q4 + 3]};
    *(float*)(slot + 4096 + lane * 4) = l;
  }
}

// merge kq partial slots of one (b, qt) -> normalized d_out
__global__ void __launch_bounds__(128)
merge_kernel(const char* __restrict__ parts, float* __restrict__ Og,
             int M, int U) {
  const int bid = blockIdx.x;
  const int b = bid & 7, qt = bid >> 3;
  const int a = qt / M;
  const int kq = a + 1;
  if (kq == 1) return;  // solo waves already wrote d_out
  const int tid = threadIdx.x;
  const int ws = tid >> 6;
  const int lane = tid & 63;
  const int base_u = (M * a * (a + 1)) / 2 + (qt - a * M) * (a + 1);

  float acc[32];
#pragma unroll
  for (int i = 0; i < 32; ++i) acc[i] = 0.0f;
  float L = 0.0f;
  for (int s2 = 0; s2 < kq; ++s2) {
    const char* slot =
        parts + (((size_t)b * U + base_u + s2) * 2 + ws) * SLOT_BYTES;
    const uint4v* src = (const uint4v*)(slot + lane * 64);
#pragma unroll
    for (int q4 = 0; q4 < 4; ++q4) {
      uint4v wv = src[q4];
#pragma unroll
      for (int e = 0; e < 4; ++e) {
        unsigned uw = wv[e];
        acc[2 * (4 * q4 + e)] += __builtin_bit_cast(float, uw << 16);
        acc[2 * (4 * q4 + e) + 1] += __builtin_bit_cast(float, uw & 0xFFFF0000u);
      }
    }
    L += *(const float*)(slot + 4096 + lane * 4);
  }
  float linv = 1.0f / L;
  const int q31 = lane & 31;
  const int h = lane >> 5;
  float* orow = Og + ((size_t)(b * S_N) + qt * 64 + ws * 32 + q31) * D_N;
#pragma unroll
  for (int dt = 0; dt < 2; ++dt)
#pragma unroll
    for (int g = 0; g < 4; ++g) {
      f32x4 w = {acc[dt * 16 + 4 * g + 0] * linv, acc[dt * 16 + 4 * g + 1] * linv,
                 acc[dt * 16 + 4 * g + 2] * linv, acc[dt * 16 + 4 * g + 3] * linv};
      *(f32x4*)(orow + dt * 32 + 8 * g + 4 * h) = w;
    }
}

extern "C" void kernel_launch(void* const* d_in, const int* in_sizes, int n_in,
                              void* d_out, int out_size, void* d_ws, size_t ws_size,
                              hipStream_t stream) {
  const float* Qg = (const float*)d_in[0];
  const float* Kg = (const float*)d_in[1];
  const float* Vg = (const float*)d_in[2];
  const unsigned* mask = (const unsigned*)d_in[3];
  float* Og = (float*)d_out;

  int* lens = (int*)d_ws;
  char* Ks = (char*)d_ws + 4096;
  char* VTs = Ks + (size_t)B_N * NQT * TILE_BYTES;    // +4MB
  char* parts = VTs + (size_t)B_N * NQT * TILE_BYTES; // +4MB

  // M = max tiles per wave; U = slots per batch = M*A*(A+1)/2, A = 64/M
  int M = 8, U = 288;
  size_t need = 4096 + ((size_t)2 * B_N * NQT * TILE_BYTES) +
                (size_t)B_N * 288 * 2 * SLOT_BYTES;   // ~28.1MB
  if (ws_size < need) { M = 64; U = 64; }             // no split, no partials

  lens_kernel<<<dim3(B_N), dim3(256), 0, stream>>>(mask, lens);
  prep_kernel<<<dim3(B_N * NQT), dim3(256), 0, stream>>>(Kg, Vg, Ks, VTs);
  // 4 independent waves per block: tasks 2U per batch, 4 per block
  attn_kernel<<<dim3(B_N * U / 2), dim3(256), 0, stream>>>(Qg, Ks, VTs, lens,
                                                           Og, parts, M, U);
  if (M == 8)
    merge_kernel<<<dim3(B_N * NQT), dim3(128), 0, stream>>>(parts, Og, M, U);
}